// Round 1
// baseline (360.893 us; speedup 1.0000x reference)
//
#include <hip/hip_runtime.h>

// Problem constants (match reference): B=16, T=8192, C=512, Y=256
#define BB 16
#define TT 8192
#define CC 512
#define YY 256
#define C4 128   // C/4 float4 lanes per frame

// One block per (b, y) phoneme span.
//   Phase 1: start = sum_{i<y} dur[b,i] via masked block reduction (durations
//            row is cache-hot across the 256 blocks of a batch).
//   Phase 2: mean-pool frames [start, end) clamped to [0,T]: 128 float4 lanes
//            cover C=512 (coalesced 2 KiB/frame), two frames in flight via
//            thread = (c4, frame_parity), pair-combined through LDS.
// Empty spans write exact zeros (also initializes poisoned d_out).
__global__ __launch_bounds__(256) void emg_pool_kernel(
    const float* __restrict__ emg,   // (B, T, C) fp32
    const int*   __restrict__ dur,   // (B, Y) int32
    float*       __restrict__ out)   // (B, Y, C) fp32
{
    const int y   = blockIdx.x;
    const int b   = blockIdx.y;
    const int tid = threadIdx.x;

    // ---- Phase 1: span bounds -------------------------------------------
    const int* drow = dur + b * YY;
    int v = (tid < y) ? drow[tid] : 0;           // masked: sum of dur[0..y-1]
    #pragma unroll
    for (int off = 32; off > 0; off >>= 1) v += __shfl_down(v, off, 64);
    __shared__ int partial[4];
    if ((tid & 63) == 0) partial[tid >> 6] = v;
    __syncthreads();
    const int s   = partial[0] + partial[1] + partial[2] + partial[3];
    const int e   = s + drow[y];
    const int sc  = (s < TT) ? s : TT;           // s >= 0 always (dur >= 0)
    const int ec  = (e < TT) ? e : TT;
    const int cnt = ec - sc;                     // frames in span (>= 0)

    // ---- Phase 2: pooled mean -------------------------------------------
    const int c4 = tid & (C4 - 1);               // which float4 of the frame
    const int fo = tid >> 7;                     // frame parity: 0 or 1
    const float4* src = (const float4*)emg + (size_t)b * TT * C4 + c4;

    float4 acc = make_float4(0.f, 0.f, 0.f, 0.f);
    #pragma unroll 4
    for (int t = sc + fo; t < ec; t += 2) {
        float4 x = src[(size_t)t * C4];
        acc.x += x.x; acc.y += x.y; acc.z += x.z; acc.w += x.w;
    }

    __shared__ float4 red[C4];                   // 2 KiB pair-combine buffer
    if (fo == 1) red[c4] = acc;
    __syncthreads();
    if (fo == 0) {
        float4 o = make_float4(0.f, 0.f, 0.f, 0.f);
        if (cnt > 0) {
            const float inv = 1.0f / (float)cnt;
            const float4 r = red[c4];
            o.x = (acc.x + r.x) * inv;
            o.y = (acc.y + r.y) * inv;
            o.z = (acc.z + r.z) * inv;
            o.w = (acc.w + r.w) * inv;
        }
        ((float4*)out)[((size_t)b * YY + y) * C4 + c4] = o;
    }
}

extern "C" void kernel_launch(void* const* d_in, const int* in_sizes, int n_in,
                              void* d_out, int out_size, void* d_ws, size_t ws_size,
                              hipStream_t stream) {
    const float* emg = (const float*)d_in[0];    // (16, 8192, 512) fp32
    const int*   dur = (const int*)d_in[1];      // (16, 256) int32
    float*       out = (float*)d_out;            // (16, 256, 512) fp32

    dim3 grid(YY, BB);   // 256 x 16 = 4096 blocks
    emg_pool_kernel<<<grid, 256, 0, stream>>>(emg, dur, out);
}